// Round 3
// baseline (156.997 us; speedup 1.0000x reference)
//
#include <hip/hip_runtime.h>
#include <hip/hip_fp16.h>
#include <math.h>
#include <stdint.h>

// SupConLossTopK, K=8192, D=256, 64 labels, T=0.1, MAX_POS=6, NEG_K=30.
// Round 13 = round-12 + k_final fused into k_anchor (last-block-done):
//  - k_prep : unchanged except it zeroes the g_done counter (ws is 0xAA-
//             poisoned each iter, so the counter must be cleared by a
//             kernel that runs before k_anchor).
//  - k_gram : unchanged (MFMA 32x32x16_f16, 64x64 tiles, XOR-swizzled LDS;
//             round-12 measured −10.7us vs VALU-dot gram).
//  - k_anchor: round-9 body + tail: after g_part[i] store, device-scope
//             release fence + atomicAdd on g_done; the 2048th block does the
//             8192-float mean and writes out[0]. Removes one dispatch + one
//             inter-dispatch gap (~6us each per the 8-dispatch/iter layout:
//             fill IDs all ==5 mod 8).
//  - k_final : REMOVED (fused).
// No same-address hot atomics (r4 lesson) — g_done is touched once per block
// (2048 total, one line, but 1 op/block not 16k on one line).
// Harness floor inside dur_us: ~44us 0xAA poison of 256MiB ws + restore +
// graph node gaps.
// exp(sim - rowmax) ratios == exp(sim) ratios -> no rowmax pass.

#define NEGK 30
#define MAXP 6
#define MAXBC 320   // max bucket rows (actual ~128 +-11; P(>320) ~ 1e-60)
#define GT 64       // gram tile dim (64x64 per block)

typedef _Float16 h2v __attribute__((ext_vector_type(2)));
typedef _Float16 f16x8 __attribute__((ext_vector_type(8)));
typedef float f32x16 __attribute__((ext_vector_type(16)));

__device__ __forceinline__ uint64_t mix64(uint64_t z) {
  z += 0x9E3779B97F4A7C15ULL;
  z = (z ^ (z >> 30)) * 0xBF58476D1CE4E5B9ULL;
  z = (z ^ (z >> 27)) * 0x94D049BB133111EBULL;
  return z ^ (z >> 31);
}

__device__ __forceinline__ float wave_reduce_add(float p) {
#pragma unroll
  for (int o = 32; o; o >>= 1) p += __shfl_down(p, o, 64);
  return p;  // lane 0
}

// dot of 8 packed halfs (one 16B chunk) accumulated into acc
__device__ __forceinline__ float dot8h(uint4 a, uint4 b, float acc) {
  const h2v* pa = (const h2v*)&a;
  const h2v* pb = (const h2v*)&b;
#if __has_builtin(__builtin_amdgcn_fdot2)
#pragma unroll
  for (int q = 0; q < 4; ++q) acc = __builtin_amdgcn_fdot2(pa[q], pb[q], acc, false);
#else
#pragma unroll
  for (int q = 0; q < 4; ++q)
    acc += (float)pa[q].x * (float)pb[q].x + (float)pa[q].y * (float)pb[q].y;
#endif
  return acc;
}

// ---- fused: blocks 0..K/4-1 normalize rows -> fp16; block K/4 bucket sort --
__global__ __launch_bounds__(256) void k_prep(const float* __restrict__ F,
                                              const int* __restrict__ labels, int K,
                                              __half* __restrict__ Fh,
                                              int* __restrict__ g_start,
                                              int* __restrict__ g_soff,
                                              int* __restrict__ g_bucket,
                                              int4* __restrict__ g_meta,
                                              int* __restrict__ g_done) {
  __shared__ int cnt[64], start[65], cur[64], soff_s[64];
  const int tid = threadIdx.x;

  if ((int)blockIdx.x < K / 4) {
    const int row = blockIdx.x * 4 + (tid >> 6);
    const int lane = tid & 63;
    const float4 a = ((const float4*)(F + (size_t)row * 256))[lane];
    float p = a.x * a.x + a.y * a.y + a.z * a.z + a.w * a.w;
    p = wave_reduce_add(p);
    p = __shfl(p, 0, 64);
    const float inv = 1.0f / fmaxf(sqrtf(p), 1e-12f);
    union { __half2 h[2]; uint2 u; } cv;
    cv.h[0] = __float22half2_rn(make_float2(a.x * inv, a.y * inv));
    cv.h[1] = __float22half2_rn(make_float2(a.z * inv, a.w * inv));
    ((uint2*)(Fh + (size_t)row * 256))[lane] = cv.u;
    return;
  }

  // bucket block
  if (tid == 0) g_done[0] = 0;  // ws is 0xAA-poisoned; clear completion ctr
  if (tid < 64) cnt[tid] = 0;
  __syncthreads();
  for (int t = tid; t < K; t += 256) atomicAdd(&cnt[labels[t] & 63], 1);
  __syncthreads();
  if (tid == 0) {
    int acc = 0, sacc = 0;
    for (int l = 0; l < 64; ++l) {
      start[l] = acc;
      const int B = cnt[l];
      acc += B;
      soff_s[l] = sacc;
      const int Bc = B < MAXBC ? B : MAXBC;
      sacc += Bc * Bc;
    }
    start[64] = acc;
  }
  __syncthreads();
  if (tid < 64) { cur[tid] = start[tid]; g_soff[tid] = soff_s[tid]; }
  if (tid < 65) g_start[tid] = start[tid];
  __syncthreads();
  for (int t = tid; t < K; t += 256) {
    const int l = labels[t] & 63;
    const int p = atomicAdd(&cur[l], 1);
    g_bucket[p] = t;
    g_meta[t] = make_int4(start[l], cnt[l], p - start[l], soff_s[l]);
  }
}

// ---- per-bucket Gram (sim*10, diag=-3e38) via MFMA: 64x64 tiles ----
// 4 waves/block, each owns a 32x32 sub-tile; K=256 fully staged in LDS.
// LDS chunk swizzle: 16B slot' = slot ^ (row&31) -> stage writes (fixed row,
// chunks 0..31) and fragment reads (rows 0..31, fixed slot) both hit 32
// distinct slots => floor-rate, no extra serialization.
__global__ __launch_bounds__(256) void k_gram(const __half* __restrict__ Fh,
                                              const int* __restrict__ g_start,
                                              const int* __restrict__ g_soff,
                                              const int* __restrict__ g_bucket,
                                              float* __restrict__ g_sims) {
  __shared__ uint4 sR[64 * 32];  // 64 row-rows   x 512B = 32KB
  __shared__ uint4 sC[64 * 32];  // 64 col-rows   x 512B = 32KB

  const int b  = blockIdx.x;
  const int bs = g_start[b];
  const int B  = g_start[b + 1] - bs;
  const int Bc = B < MAXBC ? B : MAXBC;
  if (Bc <= 0) return;  // defensive (empty bucket; unreachable in practice)
  const int r0 = blockIdx.y * GT;
  const int c0 = blockIdx.z * GT;
  if (r0 >= Bc || c0 >= Bc) return;
  const int tid = threadIdx.x;

  // stage 64 row-rows + 64 col-rows (clamped gather), swizzled chunk slots.
  // 32 consecutive threads cover one row's 512B -> coalesced global reads;
  // distinct swizzled slots -> conflict-free LDS writes.
  for (int u = tid; u < 64 * 32; u += 256) {
    const int r = u >> 5, ch = u & 31;
    const int sl = ch ^ (r & 31);
    const int rr = r0 + r;
    const int gr = g_bucket[bs + (rr < Bc ? rr : Bc - 1)];
    sR[(r << 5) | sl] = ((const uint4*)(Fh + (size_t)gr * 256))[ch];
    const int cc = c0 + r;
    const int gc = g_bucket[bs + (cc < Bc ? cc : Bc - 1)];
    sC[(r << 5) | sl] = ((const uint4*)(Fh + (size_t)gc * 256))[ch];
  }
  __syncthreads();

  const int wv = tid >> 6, lane = tid & 63;
  const int wr = (wv >> 1) * 32;        // sub-tile row base (0/32)
  const int wc = (wv & 1) * 32;         // sub-tile col base (0/32)
  const int rA = wr + (lane & 31);      // block-local A row
  const int rB = wc + (lane & 31);      // block-local B row (gram column)
  const int kq = lane >> 5;             // 0/1 -> +8 halfs within 16-half K-step

  f32x16 acc;
#pragma unroll
  for (int q = 0; q < 16; ++q) acc[q] = 0.0f;

  // A frag: row = lane&31, k = (lane>>5)*8 + e (8 contiguous f16 = one b128)
  // B frag: col = lane&31, same k split. K=256 -> 16 MFMAs.
#pragma unroll
  for (int it = 0; it < 16; ++it) {
    const int slot = 2 * it + kq;
    const f16x8 a  = *(const f16x8*)&sR[(rA << 5) | (slot ^ (rA & 31))];
    const f16x8 bf = *(const f16x8*)&sC[(rB << 5) | (slot ^ (rB & 31))];
    acc = __builtin_amdgcn_mfma_f32_32x32x16_f16(a, bf, acc, 0, 0, 0);
  }

  // C/D layout (verified): col = lane&31, row = (reg&3) + 8*(reg>>2) + 4*(lane>>5)
  float* outb = g_sims + g_soff[b];
  const int ccs = c0 + wc + (lane & 31);
  const bool cok = ccs < Bc;
#pragma unroll
  for (int reg = 0; reg < 16; ++reg) {
    const int row = (reg & 3) + 8 * (reg >> 2) + 4 * (lane >> 5);
    const int rrs = r0 + wr + row;
    if (cok && rrs < Bc)
      outb[(size_t)rrs * Bc + ccs] = (rrs == ccs) ? -3.0e38f : acc[reg] * 10.0f;
  }
}

// ---- per-anchor: one wave; value-only argmax + dual-chain negatives ----
// + fused final mean via last-block-done (device-scope counter)
__global__ __launch_bounds__(256) void k_anchor(
    const __half* __restrict__ Fh, const int* __restrict__ g_bucket,
    const int4* __restrict__ g_meta, const float* __restrict__ g_sims,
    float* __restrict__ g_part, int* __restrict__ g_done,
    float* __restrict__ out, int K) {
  __shared__ uint4 sA[4 * 32];        // 4 waves x 512B anchor rows
  __shared__ float sRed[4];
  __shared__ int sLast;
  const int wv = threadIdx.x >> 6;
  const int lane = threadIdx.x & 63;
  const int i = blockIdx.x * 4 + wv;  // K multiple of 4

  // stage anchor row into wave-private LDS (independent of meta)
  ((uint2*)sA)[wv * 64 + lane] = ((const uint2*)(Fh + (size_t)i * 256))[lane];
  const uint4* sw = sA + wv * 32;

  const int4 mt = g_meta[i];          // (bucket_start, bucket_size, loc, soff)
  const int bs = mt.x, B = mt.y;
  const int Bc = B < MAXBC ? B : MAXBC;
  int loc = mt.z;
  if (loc >= Bc) loc = 0;             // unreachable in practice
  const int n_pos = B - 1;
  const int n_neg = K - B;
  const float* simrow = g_sims + mt.w + (size_t)loc * Bc;

  // sim row -> 5 registers (Bc <= 320)
  float v[5];
#pragma unroll
  for (int rr = 0; rr < 5; ++rr) {
    const int t = lane + rr * 64;
    v[rr] = (t < Bc) ? simrow[t] : -3.4e38f;
  }

  int t6 = n_neg < MAXP ? n_neg : MAXP;
  if (t6 < 1) t6 = 1;
  int take = n_pos < t6 ? n_pos : t6;
  if (n_pos <= 0 || n_neg <= 0) take = 0;
  const int target = (take > 0) ? (n_neg < NEGK ? n_neg : NEGK) : 0;

  // ---- negatives first (kick off the gathers): dual independent chains ----
  const int s = lane & 3, g = lane >> 2;
  const int n0 = g, n1 = 16 + g;
  const uint64_t z0 = mix64(((uint64_t)(uint32_t)i << 32) | (uint32_t)n0);
  const uint64_t z1 = mix64(((uint64_t)(uint32_t)i << 32) | (uint32_t)n1);
  const unsigned int r0 = (unsigned int)(((uint64_t)(uint32_t)z0 * (uint64_t)n_neg) >> 32);
  const unsigned int r1 = (unsigned int)(((uint64_t)(uint32_t)z1 * (uint64_t)n_neg) >> 32);
  const int pos0 = (r0 < (unsigned int)bs) ? (int)r0 : (int)r0 + B;
  const int pos1 = (r1 < (unsigned int)bs) ? (int)r1 : (int)r1 + B;
  const bool pv0 = (n0 < target), pv1 = (n1 < target);
  const int j0 = pv0 ? g_bucket[pos0] : 0;
  const int j1 = pv1 ? g_bucket[pos1] : 0;
  const uint4* f0 = (const uint4*)(Fh + (size_t)j0 * 256);
  const uint4* f1 = (const uint4*)(Fh + (size_t)j1 * 256);
  float d0 = 0.0f, d1 = 0.0f;
#pragma unroll
  for (int k = 0; k < 8; ++k) {
    const uint4 aw = sw[k * 4 + s];   // LDS 4-address multicast (conflict-free)
    d0 = dot8h(f0[k * 4 + s], aw, d0);
    d1 = dot8h(f1[k * 4 + s], aw, d1);
  }
  d0 += __shfl_xor(d0, 1, 64); d0 += __shfl_xor(d0, 2, 64);
  d1 += __shfl_xor(d1, 1, 64); d1 += __shfl_xor(d1, 2, 64);
  float e = 0.0f;
  if (s == 0) {
    if (pv0) e += expf(d0 * 10.0f);
    if (pv1) e += expf(d1 * 10.0f);
  }
  const float wsum = wave_reduce_add(e);

  // ---- top-take positives: value-only max + exclude-by-equality ----
  float num = 0.0f;
  for (int r = 0; r < take; ++r) {
    float best = v[0];
#pragma unroll
    for (int c = 1; c < 5; ++c) best = fmaxf(best, v[c]);
#pragma unroll
    for (int o = 1; o < 64; o <<= 1) best = fmaxf(best, __shfl_xor(best, o, 64));
    num += expf(best);
#pragma unroll
    for (int c = 0; c < 5; ++c)
      if (v[c] == best) v[c] = -3.4e38f;
  }

  if (lane == 0) {
    float ls = 0.0f;
    if (take > 0) {
      const float denom = num + wsum;
      float ratio = denom > 0.0f ? num / denom : 0.0f;
      ratio = fmaxf(ratio, 1e-8f);
      ls = -logf(ratio);
    }
    g_part[i] = ls;                   // plain store, no atomics
  }

  // ---- last-block-done: fused mean reduction ----
  __syncthreads();                    // all 4 waves' g_part stores issued
  if (threadIdx.x == 0) {
    __threadfence();                  // release g_part to device scope
    const int prev = atomicAdd(g_done, 1);
    sLast = (prev == (int)gridDim.x - 1) ? 1 : 0;
  }
  __syncthreads();
  if (sLast) {
    __threadfence();                  // acquire: see all g_part writes
    float p = 0.0f;
    for (int t = threadIdx.x; t < K; t += 256) p += g_part[t];
    p = wave_reduce_add(p);
    if (lane == 0) sRed[wv] = p;
    __syncthreads();
    if (threadIdx.x == 0) {
      float tot = sRed[0] + sRed[1] + sRed[2] + sRed[3];
      out[0] = tot / (float)K;
    }
  }
}

extern "C" void kernel_launch(void* const* d_in, const int* in_sizes, int n_in,
                              void* d_out, int out_size, void* d_ws, size_t ws_size,
                              hipStream_t stream) {
  (void)n_in; (void)out_size; (void)ws_size;
  const float* F = (const float*)d_in[0];
  const int* labels = (const int*)d_in[1];
  const int K = in_sizes[1];  // 8192; D=256 hard-assumed
  float* out = (float*)d_out;

  char* ws = (char*)d_ws;
  size_t off = 0;
  int*   g_start  = (int*)(ws + off);   off += 512;
  int*   g_soff   = (int*)(ws + off);   off += 256;
  int*   g_done   = (int*)(ws + off);   off += 256;
  int*   g_bucket = (int*)(ws + off);   off += (size_t)K * 4;
  float* g_part   = (float*)(ws + off); off += (size_t)K * 4;
  off = (off + 255) & ~(size_t)255;
  int4*  g_meta   = (int4*)(ws + off);  off += (size_t)K * 16;
  __half* Fh      = (__half*)(ws + off); off += (size_t)K * 256 * 2;
  float* g_sims   = (float*)(ws + off);  off += (size_t)MAXBC * K * 4;

  k_prep<<<K / 4 + 1, 256, 0, stream>>>(F, labels, K, Fh, g_start, g_soff,
                                        g_bucket, g_meta, g_done);
  {
    dim3 grid(64, (MAXBC + GT - 1) / GT, (MAXBC + GT - 1) / GT);
    k_gram<<<grid, 256, 0, stream>>>(Fh, g_start, g_soff, g_bucket, g_sims);
  }
  k_anchor<<<K / 4, 256, 0, stream>>>(Fh, g_bucket, g_meta, g_sims, g_part,
                                      g_done, out, K);
}

// Round 4
// 107.289 us; speedup vs baseline: 1.4633x; 1.4633x over previous
//
#include <hip/hip_runtime.h>
#include <hip/hip_fp16.h>
#include <math.h>
#include <stdint.h>

// SupConLossTopK, K=8192, D=256, 64 labels, T=0.1, MAX_POS=6, NEG_K=30.
// Round 14 = round-12 revert (105.07us measured) + global-fed MFMA gram:
//  - k_prep : round-12 version (fused normalize->fp16 + bucket sort + meta).
//  - k_gram : MFMA 32x32x16_f16, 64x64 tiles — now fed DIRECTLY from Fh
//             (no LDS, no staging loop, no barrier). Per lane: 2 row
//             pointers, 32 independent 16B loads (L1/L2-resident; Fh=4MB
//             ~ XCD-L2-resident; 64-row panel = 32KB ~ L1). Bitwise-same
//             g_sims as round-12 (same operands, same MFMA).
//  - k_anchor: round-9 version, UNTOUCHED (round-13's fused-atomic tail
//             REVERTED: 2048 threadfence+same-line-atomicAdd arrivals cost
//             ~33ns each = +52us measured. Lesson: no device-scope arrive
//             patterns on this chip — grid.sync() would pay the same).
//  - k_final : restored (separate tiny dispatch is cheaper than any fusion
//             mechanism we have).
// No same-address global atomics anywhere (r4+r13 lessons). Gathered 16B
// streams amortized over >=4-lane row groups (r8 lesson).
// Harness floor inside dur_us: ~44us 0xAA poison of 256MiB ws + restore +
// graph node gaps.
// exp(sim - rowmax) ratios == exp(sim) ratios -> no rowmax pass.

#define NEGK 30
#define MAXP 6
#define MAXBC 320   // max bucket rows (actual ~128 +-11; P(>320) ~ 1e-60)
#define GT 64       // gram tile dim (64x64 per block)

typedef _Float16 h2v __attribute__((ext_vector_type(2)));
typedef _Float16 f16x8 __attribute__((ext_vector_type(8)));
typedef float f32x16 __attribute__((ext_vector_type(16)));

__device__ __forceinline__ uint64_t mix64(uint64_t z) {
  z += 0x9E3779B97F4A7C15ULL;
  z = (z ^ (z >> 30)) * 0xBF58476D1CE4E5B9ULL;
  z = (z ^ (z >> 27)) * 0x94D049BB133111EBULL;
  return z ^ (z >> 31);
}

__device__ __forceinline__ float wave_reduce_add(float p) {
#pragma unroll
  for (int o = 32; o; o >>= 1) p += __shfl_down(p, o, 64);
  return p;  // lane 0
}

// dot of 8 packed halfs (one 16B chunk) accumulated into acc
__device__ __forceinline__ float dot8h(uint4 a, uint4 b, float acc) {
  const h2v* pa = (const h2v*)&a;
  const h2v* pb = (const h2v*)&b;
#if __has_builtin(__builtin_amdgcn_fdot2)
#pragma unroll
  for (int q = 0; q < 4; ++q) acc = __builtin_amdgcn_fdot2(pa[q], pb[q], acc, false);
#else
#pragma unroll
  for (int q = 0; q < 4; ++q)
    acc += (float)pa[q].x * (float)pb[q].x + (float)pa[q].y * (float)pb[q].y;
#endif
  return acc;
}

// ---- fused: blocks 0..K/4-1 normalize rows -> fp16; block K/4 bucket sort --
__global__ __launch_bounds__(256) void k_prep(const float* __restrict__ F,
                                              const int* __restrict__ labels, int K,
                                              __half* __restrict__ Fh,
                                              int* __restrict__ g_start,
                                              int* __restrict__ g_soff,
                                              int* __restrict__ g_bucket,
                                              int4* __restrict__ g_meta) {
  __shared__ int cnt[64], start[65], cur[64], soff_s[64];
  const int tid = threadIdx.x;

  if ((int)blockIdx.x < K / 4) {
    const int row = blockIdx.x * 4 + (tid >> 6);
    const int lane = tid & 63;
    const float4 a = ((const float4*)(F + (size_t)row * 256))[lane];
    float p = a.x * a.x + a.y * a.y + a.z * a.z + a.w * a.w;
    p = wave_reduce_add(p);
    p = __shfl(p, 0, 64);
    const float inv = 1.0f / fmaxf(sqrtf(p), 1e-12f);
    union { __half2 h[2]; uint2 u; } cv;
    cv.h[0] = __float22half2_rn(make_float2(a.x * inv, a.y * inv));
    cv.h[1] = __float22half2_rn(make_float2(a.z * inv, a.w * inv));
    ((uint2*)(Fh + (size_t)row * 256))[lane] = cv.u;
    return;
  }

  // bucket block
  if (tid < 64) cnt[tid] = 0;
  __syncthreads();
  for (int t = tid; t < K; t += 256) atomicAdd(&cnt[labels[t] & 63], 1);
  __syncthreads();
  if (tid == 0) {
    int acc = 0, sacc = 0;
    for (int l = 0; l < 64; ++l) {
      start[l] = acc;
      const int B = cnt[l];
      acc += B;
      soff_s[l] = sacc;
      const int Bc = B < MAXBC ? B : MAXBC;
      sacc += Bc * Bc;
    }
    start[64] = acc;
  }
  __syncthreads();
  if (tid < 64) { cur[tid] = start[tid]; g_soff[tid] = soff_s[tid]; }
  if (tid < 65) g_start[tid] = start[tid];
  __syncthreads();
  for (int t = tid; t < K; t += 256) {
    const int l = labels[t] & 63;
    const int p = atomicAdd(&cur[l], 1);
    g_bucket[p] = t;
    g_meta[t] = make_int4(start[l], cnt[l], p - start[l], soff_s[l]);
  }
}

// ---- per-bucket Gram (sim*10, diag=-3e38) via MFMA: 64x64 tiles ----
// Global-fed: no LDS, no staging, no barrier. 4 waves/block, each owns a
// 32x32 sub-tile. Per lane: A-row/B-row pointers into Fh; 32 independent
// 16B loads feed 16 MFMAs. Fh (4MB) is XCD-L2-resident; block's 64-row
// panels (2x32KB) mostly L1-hit across the 4 waves.
__global__ __launch_bounds__(256, 4) void k_gram(const __half* __restrict__ Fh,
                                                 const int* __restrict__ g_start,
                                                 const int* __restrict__ g_soff,
                                                 const int* __restrict__ g_bucket,
                                                 float* __restrict__ g_sims) {
  const int b  = blockIdx.x;
  const int bs = g_start[b];
  const int B  = g_start[b + 1] - bs;
  const int Bc = B < MAXBC ? B : MAXBC;
  if (Bc <= 0) return;  // defensive (empty bucket; unreachable in practice)
  const int r0 = blockIdx.y * GT;
  const int c0 = blockIdx.z * GT;
  if (r0 >= Bc || c0 >= Bc) return;

  const int tid = threadIdx.x;
  const int wv = tid >> 6, lane = tid & 63;
  const int wr = (wv >> 1) * 32;        // sub-tile row base (0/32)
  const int wc = (wv & 1) * 32;        // sub-tile col base (0/32)
  const int rA = r0 + wr + (lane & 31); // bucket-local A row
  const int rB = c0 + wc + (lane & 31); // bucket-local B row (gram column)
  const int kq = lane >> 5;             // 0/1 -> +8 halfs within 16-half K-step

  const int gA = g_bucket[bs + (rA < Bc ? rA : Bc - 1)];
  const int gB = g_bucket[bs + (rB < Bc ? rB : Bc - 1)];
  const uint4* pA = (const uint4*)(Fh + (size_t)gA * 256) + kq;
  const uint4* pB = (const uint4*)(Fh + (size_t)gB * 256) + kq;

  f32x16 acc;
#pragma unroll
  for (int q = 0; q < 16; ++q) acc[q] = 0.0f;

  // A frag: row = lane&31, k = (lane>>5)*8 + e (8 contiguous f16 = one 16B load)
  // B frag: col = lane&31, same k split. K=256 -> 16 MFMAs, 32 indep loads.
#pragma unroll
  for (int it = 0; it < 16; ++it) {
    const f16x8 a  = *(const f16x8*)(pA + 2 * it);
    const f16x8 bf = *(const f16x8*)(pB + 2 * it);
    acc = __builtin_amdgcn_mfma_f32_32x32x16_f16(a, bf, acc, 0, 0, 0);
  }

  // C/D layout (verified): col = lane&31, row = (reg&3) + 8*(reg>>2) + 4*(lane>>5)
  float* outb = g_sims + g_soff[b];
  const int ccs = c0 + wc + (lane & 31);
  const bool cok = ccs < Bc;
#pragma unroll
  for (int reg = 0; reg < 16; ++reg) {
    const int row = (reg & 3) + 8 * (reg >> 2) + 4 * (lane >> 5);
    const int rrs = r0 + wr + row;
    if (cok && rrs < Bc)
      outb[(size_t)rrs * Bc + ccs] = (rrs == ccs) ? -3.0e38f : acc[reg] * 10.0f;
  }
}

// ---- per-anchor: one wave; value-only argmax + dual-chain negatives ----
// (round-9 version — strictly leaner than round-6's)
__global__ __launch_bounds__(256) void k_anchor(
    const __half* __restrict__ Fh, const int* __restrict__ g_bucket,
    const int4* __restrict__ g_meta, const float* __restrict__ g_sims,
    float* __restrict__ g_part, int K) {
  __shared__ uint4 sA[4 * 32];        // 4 waves x 512B anchor rows
  const int wv = threadIdx.x >> 6;
  const int lane = threadIdx.x & 63;
  const int i = blockIdx.x * 4 + wv;  // K multiple of 4

  // stage anchor row into wave-private LDS (independent of meta)
  ((uint2*)sA)[wv * 64 + lane] = ((const uint2*)(Fh + (size_t)i * 256))[lane];
  const uint4* sw = sA + wv * 32;

  const int4 mt = g_meta[i];          // (bucket_start, bucket_size, loc, soff)
  const int bs = mt.x, B = mt.y;
  const int Bc = B < MAXBC ? B : MAXBC;
  int loc = mt.z;
  if (loc >= Bc) loc = 0;             // unreachable in practice
  const int n_pos = B - 1;
  const int n_neg = K - B;
  const float* simrow = g_sims + mt.w + (size_t)loc * Bc;

  // sim row -> 5 registers (Bc <= 320)
  float v[5];
#pragma unroll
  for (int rr = 0; rr < 5; ++rr) {
    const int t = lane + rr * 64;
    v[rr] = (t < Bc) ? simrow[t] : -3.4e38f;
  }

  int t6 = n_neg < MAXP ? n_neg : MAXP;
  if (t6 < 1) t6 = 1;
  int take = n_pos < t6 ? n_pos : t6;
  if (n_pos <= 0 || n_neg <= 0) take = 0;
  const int target = (take > 0) ? (n_neg < NEGK ? n_neg : NEGK) : 0;

  // ---- negatives first (kick off the gathers): dual independent chains ----
  const int s = lane & 3, g = lane >> 2;
  const int n0 = g, n1 = 16 + g;
  const uint64_t z0 = mix64(((uint64_t)(uint32_t)i << 32) | (uint32_t)n0);
  const uint64_t z1 = mix64(((uint64_t)(uint32_t)i << 32) | (uint32_t)n1);
  const unsigned int r0 = (unsigned int)(((uint64_t)(uint32_t)z0 * (uint64_t)n_neg) >> 32);
  const unsigned int r1 = (unsigned int)(((uint64_t)(uint32_t)z1 * (uint64_t)n_neg) >> 32);
  const int pos0 = (r0 < (unsigned int)bs) ? (int)r0 : (int)r0 + B;
  const int pos1 = (r1 < (unsigned int)bs) ? (int)r1 : (int)r1 + B;
  const bool pv0 = (n0 < target), pv1 = (n1 < target);
  const int j0 = pv0 ? g_bucket[pos0] : 0;
  const int j1 = pv1 ? g_bucket[pos1] : 0;
  const uint4* f0 = (const uint4*)(Fh + (size_t)j0 * 256);
  const uint4* f1 = (const uint4*)(Fh + (size_t)j1 * 256);
  float d0 = 0.0f, d1 = 0.0f;
#pragma unroll
  for (int k = 0; k < 8; ++k) {
    const uint4 aw = sw[k * 4 + s];   // LDS 4-address multicast (conflict-free)
    d0 = dot8h(f0[k * 4 + s], aw, d0);
    d1 = dot8h(f1[k * 4 + s], aw, d1);
  }
  d0 += __shfl_xor(d0, 1, 64); d0 += __shfl_xor(d0, 2, 64);
  d1 += __shfl_xor(d1, 1, 64); d1 += __shfl_xor(d1, 2, 64);
  float e = 0.0f;
  if (s == 0) {
    if (pv0) e += expf(d0 * 10.0f);
    if (pv1) e += expf(d1 * 10.0f);
  }
  const float wsum = wave_reduce_add(e);

  // ---- top-take positives: value-only max + exclude-by-equality ----
  float num = 0.0f;
  for (int r = 0; r < take; ++r) {
    float best = v[0];
#pragma unroll
    for (int c = 1; c < 5; ++c) best = fmaxf(best, v[c]);
#pragma unroll
    for (int o = 1; o < 64; o <<= 1) best = fmaxf(best, __shfl_xor(best, o, 64));
    num += expf(best);
#pragma unroll
    for (int c = 0; c < 5; ++c)
      if (v[c] == best) v[c] = -3.4e38f;
  }

  if (lane == 0) {
    float ls = 0.0f;
    if (take > 0) {
      const float denom = num + wsum;
      float ratio = denom > 0.0f ? num / denom : 0.0f;
      ratio = fmaxf(ratio, 1e-8f);
      ls = -logf(ratio);
    }
    g_part[i] = ls;                   // plain store, no atomics
  }
}

// ---- reduce 8192 per-anchor losses -> mean ----
__global__ __launch_bounds__(1024) void k_final(const float* __restrict__ g_part,
                                                float* __restrict__ out, int K) {
  __shared__ float s[16];
  float p = 0.0f;
  for (int t = threadIdx.x; t < K; t += 1024) p += g_part[t];
  p = wave_reduce_add(p);
  if ((threadIdx.x & 63) == 0) s[threadIdx.x >> 6] = p;
  __syncthreads();
  if (threadIdx.x == 0) {
    float tot = 0.0f;
#pragma unroll
    for (int w = 0; w < 16; ++w) tot += s[w];
    out[0] = tot / (float)K;
  }
}

extern "C" void kernel_launch(void* const* d_in, const int* in_sizes, int n_in,
                              void* d_out, int out_size, void* d_ws, size_t ws_size,
                              hipStream_t stream) {
  (void)n_in; (void)out_size; (void)ws_size;
  const float* F = (const float*)d_in[0];
  const int* labels = (const int*)d_in[1];
  const int K = in_sizes[1];  // 8192; D=256 hard-assumed
  float* out = (float*)d_out;

  char* ws = (char*)d_ws;
  size_t off = 0;
  int*   g_start  = (int*)(ws + off);   off += 512;
  int*   g_soff   = (int*)(ws + off);   off += 256;
  int*   g_bucket = (int*)(ws + off);   off += (size_t)K * 4;
  float* g_part   = (float*)(ws + off); off += (size_t)K * 4;
  off = (off + 255) & ~(size_t)255;
  int4*  g_meta   = (int4*)(ws + off);  off += (size_t)K * 16;
  __half* Fh      = (__half*)(ws + off); off += (size_t)K * 256 * 2;
  float* g_sims   = (float*)(ws + off);  off += (size_t)MAXBC * K * 4;

  k_prep<<<K / 4 + 1, 256, 0, stream>>>(F, labels, K, Fh, g_start, g_soff,
                                        g_bucket, g_meta);
  {
    dim3 grid(64, (MAXBC + GT - 1) / GT, (MAXBC + GT - 1) / GT);
    k_gram<<<grid, 256, 0, stream>>>(Fh, g_start, g_soff, g_bucket, g_sims);
  }
  k_anchor<<<K / 4, 256, 0, stream>>>(Fh, g_bucket, g_meta, g_sims, g_part, K);
  k_final<<<1, 1024, 0, stream>>>(g_part, out, K);
}